// Round 12
// baseline (155.882 us; speedup 1.0000x reference)
//
#include <hip/hip_runtime.h>

#define Bb 16
#define Cc 256
#define HW 4096
#define Nn 65536
#define Kk 512

typedef __attribute__((ext_vector_type(4))) float f32x4;
typedef __attribute__((ext_vector_type(8))) short short8;

__device__ __forceinline__ float bf2f(unsigned int u){
  union { float f; unsigned int i; } v; v.i = u << 16; return v.f;
}
__device__ __forceinline__ unsigned short f2bf(float f){
  unsigned int i = __float_as_uint(f);
  unsigned int r = (i + 0x7fffu + ((i >> 16) & 1u)) >> 16;
  return (unsigned short)r;
}

// async global->LDS, 16B per lane; LDS dest = wave-uniform base + lane*16 (linear).
__device__ __forceinline__ void gld_lds16(const char* g, char* lbase){
#if __has_builtin(__builtin_amdgcn_global_load_lds)
  __builtin_amdgcn_global_load_lds(
      (const __attribute__((address_space(1))) unsigned int*)g,
      (__attribute__((address_space(3))) unsigned int*)lbase, 16, 0, 0);
#else
  *reinterpret_cast<int4*>(lbase + (threadIdx.x & 63) * 16) =
      *reinterpret_cast<const int4*>(g);
#endif
}

__device__ __forceinline__ void nt_store4(float* p, f32x4 v){
  __builtin_nontemporal_store(v, reinterpret_cast<f32x4*>(p));
}

// Fragment-major layout for a 512-row x 256-col operand (k-rows):
//   [kw:8][kt:4][ks:8][li:16][gr:4][e:8]  (bf16)

// ---------------- K1b: normalize codebook m -> mnf (fragment-major bf16) ----------------
__global__ __launch_bounds__(64) void k_mnorm(const float* __restrict__ m,
                                              unsigned short* __restrict__ mnf){
  int k = blockIdx.x, l = threadIdx.x;
  float4 v = *reinterpret_cast<const float4*>(m + (size_t)k * Cc + l * 4);
  float ss = v.x*v.x + v.y*v.y + v.z*v.z + v.w*v.w;
  #pragma unroll
  for (int off = 1; off < 64; off <<= 1) ss += __shfl_xor(ss, off, 64);
  float rn = 1.0f / fmaxf(sqrtf(ss), 1e-12f);
  ushort4 o;
  o.x = f2bf(v.x*rn); o.y = f2bf(v.y*rn); o.z = f2bf(v.z*rn); o.w = f2bf(v.w*rn);
  int kw = k >> 6, kt = (k >> 4) & 3, li = k & 15;
  int c0 = l * 4;
  int ks = c0 >> 5, gr = (c0 >> 3) & 3, eo = (l & 1) * 4;
  size_t off8 = ((((size_t)(kw*4 + kt)*8 + ks)*16 + li)*4 + gr)*8 + eo;
  *reinterpret_cast<ushort4*>(mnf + off8) = o;
}

// ---------------- K_prep_score: 128-px tile — load+norm+stash + GEMM1(raw)+argmax ----------------
// 512 blocks = (b, 128-px strip), 512 thr / 8 waves. Lane owns px pair (2l, 2l+1) via float2.
// Tile swizzle: ((px>>1)&7)<<4 on 16B granules (write and read must match).
__global__ __launch_bounds__(512, 2) void k_prep_score(const float* __restrict__ x,
                                                       const unsigned short* __restrict__ mnf,
                                                       float* __restrict__ rs,
                                                       unsigned short* __restrict__ xr,
                                                       int* __restrict__ eind){
  __shared__ __align__(16) char ldsB[65536];   // [128 px][512 B] raw bf16
  __shared__ float red[8][128];
  __shared__ float smax[8][128];
  __shared__ int   sidx[8][128];
  int t = threadIdx.x, w = t >> 6, l = t & 63, gr = l >> 4, li = l & 15;
  int b = blockIdx.x >> 5;
  int hw0 = (blockIdx.x & 31) << 7;
  // load: wave w covers channels w*32..+32; lane l covers px (2l, 2l+1)
  const float* src = x + ((size_t)b * Cc + w * 32) * HW + hw0 + 2 * l;
  float ss0 = 0.f, ss1 = 0.f;
  unsigned int pk0[16], pk1[16];
  #pragma unroll
  for (int cj = 0; cj < 16; ++cj){
    float2 a  = *reinterpret_cast<const float2*>(src + (size_t)(2*cj    ) * HW);
    float2 c2 = *reinterpret_cast<const float2*>(src + (size_t)(2*cj + 1) * HW);
    ss0 += a.x*a.x + c2.x*c2.x;
    ss1 += a.y*a.y + c2.y*c2.y;
    pk0[cj] = (unsigned int)f2bf(a.x) | ((unsigned int)f2bf(c2.x) << 16);
    pk1[cj] = (unsigned int)f2bf(a.y) | ((unsigned int)f2bf(c2.y) << 16);
  }
  {
    int p0 = 2 * l, p1 = 2 * l + 1;
    int sw = ((p0 >> 1) & 7) << 4;             // same for p0 and p1
    #pragma unroll
    for (int q = 0; q < 4; ++q){
      int colb = w * 64 + q * 16;
      int4 v0; v0.x = (int)pk0[q*4]; v0.y = (int)pk0[q*4+1];
      v0.z = (int)pk0[q*4+2]; v0.w = (int)pk0[q*4+3];
      *reinterpret_cast<int4*>(ldsB + p0 * 512 + (colb ^ sw)) = v0;
      int4 v1; v1.x = (int)pk1[q*4]; v1.y = (int)pk1[q*4+1];
      v1.z = (int)pk1[q*4+2]; v1.w = (int)pk1[q*4+3];
      *reinterpret_cast<int4*>(ldsB + p1 * 512 + (colb ^ sw)) = v1;
    }
    red[w][p0] = ss0; red[w][p1] = ss1;
  }
  int loff = li * 32 + gr * 8;
  // hoist GEMM ks=0 codebook loads above the barrier
  short8 bv0[4];
  #pragma unroll
  for (int nt = 0; nt < 4; ++nt)
    bv0[nt] = *reinterpret_cast<const short8*>(
        mnf + ((size_t)(w*4 + nt)*8 + 0)*512 + loff);
  __syncthreads();                             // stash + red complete
  if (t < 128){
    float s = 0.f;
    #pragma unroll
    for (int ww = 0; ww < 8; ++ww) s += red[ww][t];
    rs[(size_t)b * HW + hw0 + t] = 1.0f / fmaxf(sqrtf(s), 1e-12f);
  }
  // GEMM on raw tile: wave w owns k in [w*64, w*64+64); 128 px
  f32x4 acc[8][4];                             // [mt: px-tile][nt: k-tile]
  #pragma unroll
  for (int mt = 0; mt < 8; ++mt)
    #pragma unroll
    for (int nt = 0; nt < 4; ++nt)
      acc[mt][nt] = (f32x4){0.f,0.f,0.f,0.f};
  #pragma unroll
  for (int ks = 0; ks < 8; ++ks){
    short8 af[8];
    #pragma unroll
    for (int mt = 0; mt < 8; ++mt){
      int row = mt * 16 + li;
      af[mt] = *reinterpret_cast<const short8*>(
          ldsB + row * 512 + ((ks * 64 + gr * 16) ^ (((row >> 1) & 7) << 4)));
    }
    #pragma unroll
    for (int nt = 0; nt < 4; ++nt){
      short8 bv = (ks == 0) ? bv0[nt]
          : *reinterpret_cast<const short8*>(
                mnf + ((size_t)(w*4 + nt)*8 + ks)*512 + loff);
      #pragma unroll
      for (int mt = 0; mt < 8; ++mt)
        acc[mt][nt] = __builtin_amdgcn_mfma_f32_16x16x32_bf16(af[mt], bv, acc[mt][nt], 0, 0, 0);
    }
  }
  // per-wave argmax over its 64 k
  #pragma unroll
  for (int mt = 0; mt < 8; ++mt){
    #pragma unroll
    for (int r = 0; r < 4; ++r){
      float best = acc[mt][0][r]; int bi = w * 64 + li;
      #pragma unroll
      for (int nt = 1; nt < 4; ++nt){
        float v = acc[mt][nt][r]; int ii = w * 64 + nt * 16 + li;
        if (v > best){ best = v; bi = ii; }
      }
      #pragma unroll
      for (int off = 1; off < 16; off <<= 1){
        float ov = __shfl_xor(best, off, 64);
        int   oi = __shfl_xor(bi,   off, 64);
        if (ov > best || (ov == best && oi < bi)){ best = ov; bi = oi; }
      }
      if (li == 0){ int pr = mt * 16 + gr * 4 + r; smax[w][pr] = best; sidx[w][pr] = bi; }
    }
  }
  __syncthreads();
  if (t < 128){
    float best = smax[0][t]; int bi = sidx[0][t];
    #pragma unroll
    for (int ww = 1; ww < 8; ++ww){
      float v = smax[ww][t]; int ii = sidx[ww][t];
      if (v > best || (v == best && ii < bi)){ best = v; bi = ii; }
    }
    eind[(size_t)b * HW + hw0 + t] = bi;
  }
  // writeout raw xr (de-swizzled, px-major; 1KB-contiguous per wave)
  char* dst = reinterpret_cast<char*>(xr) + ((size_t)b * HW + hw0) * 512;
  #pragma unroll
  for (int i = 0; i < 8; ++i){
    int px = i * 16 + (t >> 5);
    int colb = (t & 31) * 16;
    int4 rv = *reinterpret_cast<const int4*>(
        ldsB + px * 512 + (colb ^ (((px >> 1) & 7) << 4)));
    *reinterpret_cast<int4*>(dst + (size_t)px * 512 + colb) = rv;
  }
}

// ---------------- K3: deterministic segment-sum (block = (k, quarter)) ----------------
__global__ __launch_bounds__(256) void k_segsum(const int* __restrict__ eind,
                                                const unsigned short* __restrict__ xr,
                                                float* __restrict__ es4,
                                                float* __restrict__ ec4){
  int kk = blockIdx.x >> 2, qr = blockIdx.x & 3;
  int t = threadIdx.x, w = t >> 6, l = t & 63;
  float a0=0.f,a1=0.f,a2=0.f,a3=0.f;
  int cnt = 0;
  int base = qr * 16384 + w * 4096;
  for (int it = 0; it < 16; ++it){
    int pxb = base + it * 256;
    int4 e = *reinterpret_cast<const int4*>(eind + pxb + l * 4);
    #pragma unroll
    for (int comp = 0; comp < 4; ++comp){
      int ev = comp == 0 ? e.x : comp == 1 ? e.y : comp == 2 ? e.z : e.w;
      unsigned long long mask = __ballot(ev == kk);
      cnt += (int)__popcll(mask);
      while (mask){
        int src = __ffsll((unsigned long long)mask) - 1;
        mask &= mask - 1;
        int px = pxb + src * 4 + comp;
        ushort4 uv = *reinterpret_cast<const ushort4*>(xr + (size_t)px * Cc + l * 4);
        a0 += bf2f(uv.x); a1 += bf2f(uv.y);
        a2 += bf2f(uv.z); a3 += bf2f(uv.w);
      }
    }
  }
  __shared__ float red[4][256];
  __shared__ float rcnt[4];
  red[w][l*4+0]=a0; red[w][l*4+1]=a1; red[w][l*4+2]=a2; red[w][l*4+3]=a3;
  if (l == 0) rcnt[w] = (float)cnt;
  __syncthreads();
  float s = red[0][t] + red[1][t] + red[2][t] + red[3][t];
  es4[(size_t)blockIdx.x * Cc + t] = s;
  if (t == 0) ec4[blockIdx.x] = rcnt[0] + rcnt[1] + rcnt[2] + rcnt[3];
}

// ---------------- K4: EMA update -> mn2f (normalized, fragment-major) + nmTf ----------------
__global__ __launch_bounds__(64) void k_update(const float* __restrict__ es4,
                                               const float* __restrict__ ec4,
                                               const float* __restrict__ m,
                                               unsigned short* __restrict__ mn2f,
                                               unsigned short* __restrict__ nmTf){
  int k = blockIdx.x, l = threadIdx.x;
  float sx = 0.f, sy = 0.f, sz = 0.f, sw = 0.f, cs = 0.f;
  #pragma unroll
  for (int q = 0; q < 4; ++q){
    float4 s = *reinterpret_cast<const float4*>(es4 + ((size_t)(4*k+q)) * Cc + l * 4);
    sx += s.x; sy += s.y; sz += s.z; sw += s.w;
    cs += ec4[4*k+q];
  }
  float4 mv = *reinterpret_cast<const float4*>(m + (size_t)k * Cc + l * 4);
  float inv = 1.0f / (cs + 1e-6f);
  float nx = mv.x * 0.999f + sx * inv * 0.001f;
  float ny = mv.y * 0.999f + sy * inv * 0.001f;
  float nz = mv.z * 0.999f + sz * inv * 0.001f;
  float nw = mv.w * 0.999f + sw * inv * 0.001f;
  float ss = nx*nx + ny*ny + nz*nz + nw*nw;
  #pragma unroll
  for (int off = 1; off < 64; off <<= 1) ss += __shfl_xor(ss, off, 64);
  float rn = 1.0f / fmaxf(sqrtf(ss), 1e-12f);
  ushort4 o;
  o.x = f2bf(nx*rn); o.y = f2bf(ny*rn); o.z = f2bf(nz*rn); o.w = f2bf(nw*rn);
  {
    int kw = k >> 6, kt = (k >> 4) & 3, li = k & 15;
    int c0 = l * 4;
    int ks = c0 >> 5, gr = (c0 >> 3) & 3, eo = (l & 1) * 4;
    size_t off8 = ((((size_t)(kw*4 + kt)*8 + ks)*16 + li)*4 + gr)*8 + eo;
    *reinterpret_cast<ushort4*>(mn2f + off8) = o;
  }
  {
    int ksn = k >> 5, grn = (k >> 3) & 3, en = k & 7;
    unsigned short nv[4] = {f2bf(nx), f2bf(ny), f2bf(nz), f2bf(nw)};
    #pragma unroll
    for (int q = 0; q < 4; ++q){
      int c = l * 4 + q;
      int cb = c >> 4, li2 = c & 15;
      size_t off8 = ((((size_t)cb*16 + ksn)*16 + li2)*4 + grn)*8 + en;
      nmTf[off8] = nv[q];
    }
  }
}

// ---------------- K5: 128-px tile, fused; async stage + prefetch + NT stores ----------------
__global__ __launch_bounds__(512, 2) void k_out(const unsigned short* __restrict__ xr,
                                                const float* __restrict__ rs,
                                                const unsigned short* __restrict__ mn2f,
                                                const unsigned short* __restrict__ nmTf,
                                                float* __restrict__ out,
                                                float* __restrict__ score2){
  __shared__ __align__(16) char smem[131072];  // stage 64K -> P 128K -> s2/out transpose tiles
  __shared__ float wbuf[8 * 128];
  __shared__ float rz[128];
  __shared__ float rsl[128];
  int t = threadIdx.x, w = t >> 6, l = t & 63, gr = l >> 4, li = l & 15;
  int px0 = blockIdx.x * 128;
  // async stage: pre-swizzled global source, linear LDS dest
  const char* gsrc = reinterpret_cast<const char*>(xr + (size_t)px0 * Cc);
  #pragma unroll
  for (int j = 0; j < 8; ++j){
    int chunk = j * 512 + t;
    int rr = chunk >> 5, slot = chunk & 31;
    const char* g = gsrc + rr * 512 + ((slot * 16) ^ ((rr & 7) << 4));
    int rr0 = (j * 512 + w * 64) >> 5;         // wave-uniform
    gld_lds16(g, smem + rr0 * 512);
  }
  int loff = li * 32 + gr * 8;
  // hoist GEMM1 ks=0 codebook loads
  short8 amc[4];
  #pragma unroll
  for (int kt = 0; kt < 4; ++kt)
    amc[kt] = *reinterpret_cast<const short8*>(
        mn2f + ((size_t)(w*4 + kt)*8 + 0)*512 + loff);
  if (t < 128) rsl[t] = rs[px0 + t];
  __syncthreads();                             // bar1: stage + rsl
  // GEMM1': A = mn2f k-rows (prefetch depth 1), B = xr px-rows -> D[row=k][col=px]
  f32x4 acc[4][8];                             // [kt][pt] : 128 px
  #pragma unroll
  for (int kt = 0; kt < 4; ++kt)
    #pragma unroll
    for (int pt = 0; pt < 8; ++pt)
      acc[kt][pt] = (f32x4){0.f,0.f,0.f,0.f};
  int kw = w * 64;
  #pragma unroll
  for (int ks = 0; ks < 8; ++ks){
    short8 amn[4];
    if (ks < 7){
      #pragma unroll
      for (int kt = 0; kt < 4; ++kt)
        amn[kt] = *reinterpret_cast<const short8*>(
            mn2f + ((size_t)(w*4 + kt)*8 + (ks+1))*512 + loff);
    }
    #pragma unroll
    for (int pt = 0; pt < 8; ++pt){
      int row = pt * 16 + li;
      short8 bx = *reinterpret_cast<const short8*>(
          smem + row * 512 + ((ks * 64 + gr * 16) ^ ((row & 7) << 4)));
      #pragma unroll
      for (int kt = 0; kt < 4; ++kt)
        acc[kt][pt] = __builtin_amdgcn_mfma_f32_16x16x32_bf16(amc[kt], bx, acc[kt][pt], 0, 0, 0);
    }
    if (ks < 7){
      #pragma unroll
      for (int kt = 0; kt < 4; ++kt) amc[kt] = amn[kt];
    }
  }
  __syncthreads();                             // bar2: xr LDS reads done before P overlay
  // scale into acc (score2 values), exp -> P bf16 LDS [128 x 1KB], partial sums
  float s[8] = {0.f,0.f,0.f,0.f,0.f,0.f,0.f,0.f};
  #pragma unroll
  for (int kt = 0; kt < 4; ++kt){
    #pragma unroll
    for (int pt = 0; pt < 8; ++pt){
      int px = pt * 16 + li;
      float rsv = rsl[px];
      f32x4 v = acc[kt][pt];
      v[0] *= rsv; v[1] *= rsv; v[2] *= rsv; v[3] *= rsv;
      acc[kt][pt] = v;                         // keep score2 values for transposed store
      float p0 = __expf(v[0]), p1 = __expf(v[1]), p2 = __expf(v[2]), p3 = __expf(v[3]);
      s[pt] += (p0 + p1) + (p2 + p3);
      unsigned int lo = (unsigned int)f2bf(p0) | ((unsigned int)f2bf(p1) << 16);
      unsigned int hi = (unsigned int)f2bf(p2) | ((unsigned int)f2bf(p3) << 16);
      int colb = (kw + kt * 16 + gr * 4) * 2;
      uint2 pv; pv.x = lo; pv.y = hi;
      *reinterpret_cast<uint2*>(smem + px * 1024 + (colb ^ ((px & 7) << 4))) = pv;
    }
  }
  #pragma unroll
  for (int pt = 0; pt < 8; ++pt){
    s[pt] += __shfl_xor(s[pt], 16, 64);
    s[pt] += __shfl_xor(s[pt], 32, 64);
  }
  if (gr == 0){
    #pragma unroll
    for (int pt = 0; pt < 8; ++pt) wbuf[w * 128 + pt * 16 + li] = s[pt];
  }
  // hoist GEMM2 ks=0 codebook loads
  short8 bvc[2];
  #pragma unroll
  for (int nt = 0; nt < 2; ++nt)
    bvc[nt] = *reinterpret_cast<const short8*>(
        nmTf + ((size_t)(w*2 + nt)*16 + 0)*512 + loff);
  __syncthreads();                             // bar3: P + wbuf(sums) ready
  if (t < 128){
    float sum = 0.f;
    #pragma unroll
    for (int ww = 0; ww < 8; ++ww) sum += wbuf[ww * 128 + t];
    rz[t] = 1.0f / sum;
  }
  // GEMM2: out tile = P @ new_m  (bv prefetch depth 1; wave w owns c in [w*32,+32))
  f32x4 acc2[8][2];                            // [mt: 128 px][nt]
  #pragma unroll
  for (int mt = 0; mt < 8; ++mt)
    #pragma unroll
    for (int nt = 0; nt < 2; ++nt)
      acc2[mt][nt] = (f32x4){0.f,0.f,0.f,0.f};
  #pragma unroll
  for (int ks = 0; ks < 16; ++ks){
    short8 bvn[2];
    if (ks < 15){
      #pragma unroll
      for (int nt = 0; nt < 2; ++nt)
        bvn[nt] = *reinterpret_cast<const short8*>(
            nmTf + ((size_t)(w*2 + nt)*16 + (ks+1))*512 + loff);
    }
    #pragma unroll
    for (int mt = 0; mt < 8; ++mt){
      int row = mt * 16 + li;
      short8 af = *reinterpret_cast<const short8*>(
          smem + row * 1024 + ((ks * 64 + gr * 16) ^ ((row & 7) << 4)));
      #pragma unroll
      for (int nt = 0; nt < 2; ++nt)
        acc2[mt][nt] = __builtin_amdgcn_mfma_f32_16x16x32_bf16(af, bvc[nt], acc2[mt][nt], 0, 0, 0);
    }
    if (ks < 15){
      #pragma unroll
      for (int nt = 0; nt < 2; ++nt) bvc[nt] = bvn[nt];
    }
  }
  __syncthreads();                             // bar4: P dead, rz visible
  // ---- score2 via LDS transpose, two 64-px halves; NT 1KB-contiguous wave stores ----
  float* s2 = score2 + (size_t)px0 * Kk;
  #pragma unroll
  for (int h = 0; h < 2; ++h){
    #pragma unroll
    for (int kt = 0; kt < 4; ++kt)
      #pragma unroll
      for (int pt2 = 0; pt2 < 4; ++pt2){
        int pxl = pt2 * 16 + li;               // local px in half
        int kb = (kw + kt * 16 + gr * 4) * 4;  // byte offset of k within row
        *reinterpret_cast<f32x4*>(smem + pxl * 2048 + (kb ^ ((pxl & 7) << 4)))
            = acc[kt][h * 4 + pt2];
      }
    __syncthreads();                           // tile ready
    #pragma unroll
    for (int r = 0; r < 8; ++r){
      int pxl = w * 8 + r;
      int px = h * 64 + pxl;
      #pragma unroll
      for (int j = 0; j < 2; ++j){
        int o = j * 1024 + l * 16;
        f32x4 v = *reinterpret_cast<const f32x4*>(smem + pxl * 2048 + (o ^ ((pxl & 7) << 4)));
        nt_store4(s2 + (size_t)px * Kk + (o >> 2), v);
      }
    }
    __syncthreads();                           // stores' LDS reads done before reuse
  }
  // ---- out via LDS transpose [256 c][512 B rows]; NT 512B-contiguous segments ----
  #pragma unroll
  for (int mt = 0; mt < 8; ++mt){
    int pb = mt * 16 + gr * 4;
    f32x4 rzv = *reinterpret_cast<const f32x4*>(&rz[pb]);
    #pragma unroll
    for (int nt = 0; nt < 2; ++nt){
      int c = w * 32 + nt * 16 + li;
      f32x4 v;
      v[0] = acc2[mt][nt][0] * rzv[0];
      v[1] = acc2[mt][nt][1] * rzv[1];
      v[2] = acc2[mt][nt][2] * rzv[2];
      v[3] = acc2[mt][nt][3] * rzv[3];
      *reinterpret_cast<f32x4*>(smem + c * 512 + ((pb * 4) ^ ((c & 7) << 4))) = v;
    }
  }
  __syncthreads();                             // out tile ready
  int b = px0 >> 12, hw0 = px0 & 4095;
  #pragma unroll
  for (int i = 0; i < 16; ++i){
    int c = w * 32 + i * 2 + (l >> 5);
    int o = (l & 31) * 16;
    f32x4 v = *reinterpret_cast<const f32x4*>(smem + c * 512 + (o ^ ((c & 7) << 4)));
    nt_store4(out + ((size_t)b * Cc + c) * HW + hw0 + (o >> 2), v);
  }
}

extern "C" void kernel_launch(void* const* d_in, const int* in_sizes, int n_in,
                              void* d_out, int out_size, void* d_ws, size_t ws_size,
                              hipStream_t stream) {
  (void)in_sizes; (void)n_in; (void)out_size; (void)ws_size;
  const float* x = (const float*)d_in[0];   // (16,256,64,64)
  const float* m = (const float*)d_in[1];   // (512,256)
  float* out    = (float*)d_out;                       // 16777216 f32
  float* score2 = (float*)d_out + (size_t)Nn * Cc;     // 33554432 f32

  char* ws = (char*)d_ws;
  unsigned short* xr   = (unsigned short*)(ws);                 // 33554432 B raw bf16 x, px-major
  float*          rsb  = (float*)(ws + 33554432);               //   262144 B  1/||x||
  unsigned short* mnf  = (unsigned short*)(ws + 33816576);      //   262144 B fragment-major
  int*            ei   = (int*)(ws + 34078720);                 //   262144 B
  float*          es4  = (float*)(ws + 34340864);               //  2097152 B
  float*          ec4  = (float*)(ws + 36438016);               //     8192 B
  unsigned short* mn2f = (unsigned short*)(ws + 36446208);      //   262144 B fragment-major
  unsigned short* nmTf = (unsigned short*)(ws + 36708352);      //   262144 B fragment-major

  k_mnorm       <<<512,  64,  0, stream>>>(m, mnf);
  k_prep_score  <<<512,  512, 0, stream>>>(x, mnf, rsb, xr, ei);
  k_segsum      <<<2048, 256, 0, stream>>>(ei, xr, es4, ec4);
  k_update      <<<512,  64,  0, stream>>>(es4, ec4, m, mn2f, nmTf);
  k_out         <<<512,  512, 0, stream>>>(xr, rsb, mn2f, nmTf, out, score2);
}

// Round 13
// 149.732 us; speedup vs baseline: 1.0411x; 1.0411x over previous
//
#include <hip/hip_runtime.h>

#define Bb 16
#define Cc 256
#define HW 4096
#define Nn 65536
#define Kk 512

typedef __attribute__((ext_vector_type(4))) float f32x4;
typedef __attribute__((ext_vector_type(8))) short short8;

__device__ __forceinline__ float bf2f(unsigned int u){
  union { float f; unsigned int i; } v; v.i = u << 16; return v.f;
}
__device__ __forceinline__ unsigned short f2bf(float f){
  unsigned int i = __float_as_uint(f);
  unsigned int r = (i + 0x7fffu + ((i >> 16) & 1u)) >> 16;
  return (unsigned short)r;
}

// async global->LDS, 16B per lane; LDS dest = wave-uniform base + lane*16 (linear).
__device__ __forceinline__ void gld_lds16(const char* g, char* lbase){
#if __has_builtin(__builtin_amdgcn_global_load_lds)
  __builtin_amdgcn_global_load_lds(
      (const __attribute__((address_space(1))) unsigned int*)g,
      (__attribute__((address_space(3))) unsigned int*)lbase, 16, 0, 0);
#else
  *reinterpret_cast<int4*>(lbase + (threadIdx.x & 63) * 16) =
      *reinterpret_cast<const int4*>(g);
#endif
}

// Fragment-major layout for a 512-row x 256-col operand (k-rows):
//   [kw:8][kt:4][ks:8][li:16][gr:4][e:8]  (bf16)

// ---------------- K1b: normalize codebook m -> mnf (fragment-major bf16) ----------------
__global__ __launch_bounds__(64) void k_mnorm(const float* __restrict__ m,
                                              unsigned short* __restrict__ mnf){
  int k = blockIdx.x, l = threadIdx.x;
  float4 v = *reinterpret_cast<const float4*>(m + (size_t)k * Cc + l * 4);
  float ss = v.x*v.x + v.y*v.y + v.z*v.z + v.w*v.w;
  #pragma unroll
  for (int off = 1; off < 64; off <<= 1) ss += __shfl_xor(ss, off, 64);
  float rn = 1.0f / fmaxf(sqrtf(ss), 1e-12f);
  ushort4 o;
  o.x = f2bf(v.x*rn); o.y = f2bf(v.y*rn); o.z = f2bf(v.z*rn); o.w = f2bf(v.w*rn);
  int kw = k >> 6, kt = (k >> 4) & 3, li = k & 15;
  int c0 = l * 4;
  int ks = c0 >> 5, gr = (c0 >> 3) & 3, eo = (l & 1) * 4;
  size_t off8 = ((((size_t)(kw*4 + kt)*8 + ks)*16 + li)*4 + gr)*8 + eo;
  *reinterpret_cast<ushort4*>(mnf + off8) = o;
}

// ---------------- K_prep_score: fused load+norm+stash + GEMM1(raw)+argmax ----------------
__global__ __launch_bounds__(512, 4) void k_prep_score(const float* __restrict__ x,
                                                       const unsigned short* __restrict__ mnf,
                                                       float* __restrict__ rs,
                                                       unsigned short* __restrict__ xr,
                                                       int* __restrict__ eind){
  __shared__ __align__(16) char ldsB[32768];   // [64 px][512 B] raw bf16, XOR-swizzled
  __shared__ float red[8][64];
  __shared__ float smax[8][64];
  __shared__ int   sidx[8][64];
  int t = threadIdx.x, w = t >> 6, l = t & 63, gr = l >> 4, li = l & 15;
  int b = blockIdx.x >> 6;
  int hw0 = (blockIdx.x & 63) << 6;
  const float* src = x + ((size_t)b * Cc + w * 32) * HW + hw0 + l;
  float ss = 0.f;
  unsigned int pk[16];
  #pragma unroll
  for (int j = 0; j < 16; ++j){
    float v0 = src[(size_t)(2*j    ) * HW];
    float v1 = src[(size_t)(2*j + 1) * HW];
    ss += v0 * v0 + v1 * v1;
    pk[j] = (unsigned int)f2bf(v0) | ((unsigned int)f2bf(v1) << 16);
  }
  #pragma unroll
  for (int q = 0; q < 4; ++q){
    int colb = w * 64 + q * 16;
    int4 vv;
    vv.x = (int)pk[q*4+0]; vv.y = (int)pk[q*4+1];
    vv.z = (int)pk[q*4+2]; vv.w = (int)pk[q*4+3];
    *reinterpret_cast<int4*>(ldsB + l * 512 + (colb ^ ((l & 7) << 4))) = vv;
  }
  red[w][l] = ss;
  int loff = li * 32 + gr * 8;
  // hoist GEMM ks=0 codebook loads above the barrier (L2 latency overlaps drain)
  short8 bv0[4];
  #pragma unroll
  for (int nt = 0; nt < 4; ++nt)
    bv0[nt] = *reinterpret_cast<const short8*>(
        mnf + ((size_t)(w*4 + nt)*8 + 0)*512 + loff);
  __syncthreads();                             // stash + red complete
  if (t < 64){
    float s = 0.f;
    #pragma unroll
    for (int ww = 0; ww < 8; ++ww) s += red[ww][t];
    rs[(size_t)b * HW + hw0 + t] = 1.0f / fmaxf(sqrtf(s), 1e-12f);
  }
  // GEMM1 on raw tile: wave w owns k in [w*64, w*64+64); mnf loads are 1KB coalesced
  f32x4 acc[4][4];
  #pragma unroll
  for (int mt = 0; mt < 4; ++mt)
    #pragma unroll
    for (int nt = 0; nt < 4; ++nt)
      acc[mt][nt] = (f32x4){0.f,0.f,0.f,0.f};
  #pragma unroll
  for (int ks = 0; ks < 8; ++ks){
    short8 af[4];
    #pragma unroll
    for (int mt = 0; mt < 4; ++mt){
      int row = mt * 16 + li;
      af[mt] = *reinterpret_cast<const short8*>(
          ldsB + row * 512 + ((ks * 64 + gr * 16) ^ ((row & 7) << 4)));
    }
    #pragma unroll
    for (int nt = 0; nt < 4; ++nt){
      short8 bv = (ks == 0) ? bv0[nt]
          : *reinterpret_cast<const short8*>(
                mnf + ((size_t)(w*4 + nt)*8 + ks)*512 + loff);
      #pragma unroll
      for (int mt = 0; mt < 4; ++mt)
        acc[mt][nt] = __builtin_amdgcn_mfma_f32_16x16x32_bf16(af[mt], bv, acc[mt][nt], 0, 0, 0);
    }
  }
  // per-wave argmax over its 64 k
  #pragma unroll
  for (int mt = 0; mt < 4; ++mt){
    #pragma unroll
    for (int r = 0; r < 4; ++r){
      float best = acc[mt][0][r]; int bi = w * 64 + li;
      #pragma unroll
      for (int nt = 1; nt < 4; ++nt){
        float v = acc[mt][nt][r]; int ii = w * 64 + nt * 16 + li;
        if (v > best){ best = v; bi = ii; }
      }
      #pragma unroll
      for (int off = 1; off < 16; off <<= 1){
        float ov = __shfl_xor(best, off, 64);
        int   oi = __shfl_xor(bi,   off, 64);
        if (ov > best || (ov == best && oi < bi)){ best = ov; bi = oi; }
      }
      if (li == 0){ int pr = mt * 16 + gr * 4 + r; smax[w][pr] = best; sidx[w][pr] = bi; }
    }
  }
  __syncthreads();
  if (t < 64){
    float best = smax[0][t]; int bi = sidx[0][t];
    #pragma unroll
    for (int ww = 1; ww < 8; ++ww){
      float v = smax[ww][t]; int ii = sidx[ww][t];
      if (v > best || (v == best && ii < bi)){ best = v; bi = ii; }
    }
    eind[(size_t)b * HW + hw0 + t] = bi;
  }
  // writeout raw xr (1KB-contiguous per wave)
  char* dst = reinterpret_cast<char*>(xr) + ((size_t)b * HW + hw0) * 512;
  #pragma unroll
  for (int i = 0; i < 4; ++i){
    int px = i * 16 + (t >> 5);
    int colb = (t & 31) * 16;
    int4 rv = *reinterpret_cast<const int4*>(ldsB + px * 512 + (colb ^ ((px & 7) << 4)));
    *reinterpret_cast<int4*>(dst + (size_t)px * 512 + colb) = rv;
  }
}

// ---------------- K3: deterministic segment-sum (block = (k, quarter)) ----------------
__global__ __launch_bounds__(256) void k_segsum(const int* __restrict__ eind,
                                                const unsigned short* __restrict__ xr,
                                                float* __restrict__ es4,
                                                float* __restrict__ ec4){
  int kk = blockIdx.x >> 2, qr = blockIdx.x & 3;
  int t = threadIdx.x, w = t >> 6, l = t & 63;
  float a0=0.f,a1=0.f,a2=0.f,a3=0.f;
  int cnt = 0;
  int base = qr * 16384 + w * 4096;
  for (int it = 0; it < 16; ++it){
    int pxb = base + it * 256;
    int4 e = *reinterpret_cast<const int4*>(eind + pxb + l * 4);
    #pragma unroll
    for (int comp = 0; comp < 4; ++comp){
      int ev = comp == 0 ? e.x : comp == 1 ? e.y : comp == 2 ? e.z : e.w;
      unsigned long long mask = __ballot(ev == kk);
      cnt += (int)__popcll(mask);
      while (mask){
        int src = __ffsll((unsigned long long)mask) - 1;
        mask &= mask - 1;
        int px = pxb + src * 4 + comp;
        ushort4 uv = *reinterpret_cast<const ushort4*>(xr + (size_t)px * Cc + l * 4);
        a0 += bf2f(uv.x); a1 += bf2f(uv.y);
        a2 += bf2f(uv.z); a3 += bf2f(uv.w);
      }
    }
  }
  __shared__ float red[4][256];
  __shared__ float rcnt[4];
  red[w][l*4+0]=a0; red[w][l*4+1]=a1; red[w][l*4+2]=a2; red[w][l*4+3]=a3;
  if (l == 0) rcnt[w] = (float)cnt;
  __syncthreads();
  float s = red[0][t] + red[1][t] + red[2][t] + red[3][t];
  es4[(size_t)blockIdx.x * Cc + t] = s;
  if (t == 0) ec4[blockIdx.x] = rcnt[0] + rcnt[1] + rcnt[2] + rcnt[3];
}

// ---------------- K4: EMA update -> mn2f (normalized, fragment-major) + nmTf ----------------
__global__ __launch_bounds__(64) void k_update(const float* __restrict__ es4,
                                               const float* __restrict__ ec4,
                                               const float* __restrict__ m,
                                               unsigned short* __restrict__ mn2f,
                                               unsigned short* __restrict__ nmTf){
  int k = blockIdx.x, l = threadIdx.x;
  float sx = 0.f, sy = 0.f, sz = 0.f, sw = 0.f, cs = 0.f;
  #pragma unroll
  for (int q = 0; q < 4; ++q){
    float4 s = *reinterpret_cast<const float4*>(es4 + ((size_t)(4*k+q)) * Cc + l * 4);
    sx += s.x; sy += s.y; sz += s.z; sw += s.w;
    cs += ec4[4*k+q];
  }
  float4 mv = *reinterpret_cast<const float4*>(m + (size_t)k * Cc + l * 4);
  float inv = 1.0f / (cs + 1e-6f);
  float nx = mv.x * 0.999f + sx * inv * 0.001f;
  float ny = mv.y * 0.999f + sy * inv * 0.001f;
  float nz = mv.z * 0.999f + sz * inv * 0.001f;
  float nw = mv.w * 0.999f + sw * inv * 0.001f;
  float ss = nx*nx + ny*ny + nz*nz + nw*nw;
  #pragma unroll
  for (int off = 1; off < 64; off <<= 1) ss += __shfl_xor(ss, off, 64);
  float rn = 1.0f / fmaxf(sqrtf(ss), 1e-12f);
  ushort4 o;
  o.x = f2bf(nx*rn); o.y = f2bf(ny*rn); o.z = f2bf(nz*rn); o.w = f2bf(nw*rn);
  {
    int kw = k >> 6, kt = (k >> 4) & 3, li = k & 15;
    int c0 = l * 4;
    int ks = c0 >> 5, gr = (c0 >> 3) & 3, eo = (l & 1) * 4;
    size_t off8 = ((((size_t)(kw*4 + kt)*8 + ks)*16 + li)*4 + gr)*8 + eo;
    *reinterpret_cast<ushort4*>(mn2f + off8) = o;
  }
  {
    int ksn = k >> 5, grn = (k >> 3) & 3, en = k & 7;
    unsigned short nv[4] = {f2bf(nx), f2bf(ny), f2bf(nz), f2bf(nw)};
    #pragma unroll
    for (int q = 0; q < 4; ++q){
      int c = l * 4 + q;
      int cb = c >> 4, li2 = c & 15;
      size_t off8 = ((((size_t)cb*16 + ksn)*16 + li2)*4 + grn)*8 + en;
      nmTf[off8] = nv[q];
    }
  }
}

// ---------------- K5: 128-px tile, fused; async stage + prefetched codebook ----------------
__global__ __launch_bounds__(512, 2) void k_out(const unsigned short* __restrict__ xr,
                                                const float* __restrict__ rs,
                                                const unsigned short* __restrict__ mn2f,
                                                const unsigned short* __restrict__ nmTf,
                                                float* __restrict__ out,
                                                float* __restrict__ score2){
  __shared__ __align__(16) char smem[131072];  // stage 64K -> P 128K -> s2/out transpose tiles
  __shared__ float wbuf[8 * 128];
  __shared__ float rz[128];
  __shared__ float rsl[128];
  int t = threadIdx.x, w = t >> 6, l = t & 63, gr = l >> 4, li = l & 15;
  int px0 = blockIdx.x * 128;
  // async stage: pre-swizzled global source, linear LDS dest (same LDS image as before)
  const char* gsrc = reinterpret_cast<const char*>(xr + (size_t)px0 * Cc);
  #pragma unroll
  for (int j = 0; j < 8; ++j){
    int chunk = j * 512 + t;
    int rr = chunk >> 5, slot = chunk & 31;
    const char* g = gsrc + rr * 512 + ((slot * 16) ^ ((rr & 7) << 4));
    int rr0 = (j * 512 + w * 64) >> 5;         // wave-uniform
    gld_lds16(g, smem + rr0 * 512);
  }
  int loff = li * 32 + gr * 8;
  // hoist GEMM1 ks=0 codebook loads (L2 latency overlaps stage + barrier)
  short8 amc[4];
  #pragma unroll
  for (int kt = 0; kt < 4; ++kt)
    amc[kt] = *reinterpret_cast<const short8*>(
        mn2f + ((size_t)(w*4 + kt)*8 + 0)*512 + loff);
  if (t < 128) rsl[t] = rs[px0 + t];
  __syncthreads();                             // bar1: stage + rsl
  // GEMM1': A = mn2f k-rows (prefetch depth 1), B = xr px-rows -> D[row=k][col=px]
  f32x4 acc[4][8];                             // [kt][pt] : 128 px
  #pragma unroll
  for (int kt = 0; kt < 4; ++kt)
    #pragma unroll
    for (int pt = 0; pt < 8; ++pt)
      acc[kt][pt] = (f32x4){0.f,0.f,0.f,0.f};
  int kw = w * 64;
  #pragma unroll
  for (int ks = 0; ks < 8; ++ks){
    short8 amn[4];
    if (ks < 7){
      #pragma unroll
      for (int kt = 0; kt < 4; ++kt)
        amn[kt] = *reinterpret_cast<const short8*>(
            mn2f + ((size_t)(w*4 + kt)*8 + (ks+1))*512 + loff);
    }
    #pragma unroll
    for (int pt = 0; pt < 8; ++pt){
      int row = pt * 16 + li;
      short8 bx = *reinterpret_cast<const short8*>(
          smem + row * 512 + ((ks * 64 + gr * 16) ^ ((row & 7) << 4)));
      #pragma unroll
      for (int kt = 0; kt < 4; ++kt)
        acc[kt][pt] = __builtin_amdgcn_mfma_f32_16x16x32_bf16(amc[kt], bx, acc[kt][pt], 0, 0, 0);
    }
    if (ks < 7){
      #pragma unroll
      for (int kt = 0; kt < 4; ++kt) amc[kt] = amn[kt];
    }
  }
  __syncthreads();                             // bar2: xr LDS reads done before P overlay
  // scale into acc (score2 values), exp -> P bf16 LDS [128 x 1KB], partial sums
  float s[8] = {0.f,0.f,0.f,0.f,0.f,0.f,0.f,0.f};
  #pragma unroll
  for (int kt = 0; kt < 4; ++kt){
    #pragma unroll
    for (int pt = 0; pt < 8; ++pt){
      int px = pt * 16 + li;
      float rsv = rsl[px];
      f32x4 v = acc[kt][pt];
      v[0] *= rsv; v[1] *= rsv; v[2] *= rsv; v[3] *= rsv;
      acc[kt][pt] = v;                         // keep score2 values for transposed store
      float p0 = __expf(v[0]), p1 = __expf(v[1]), p2 = __expf(v[2]), p3 = __expf(v[3]);
      s[pt] += (p0 + p1) + (p2 + p3);
      unsigned int lo = (unsigned int)f2bf(p0) | ((unsigned int)f2bf(p1) << 16);
      unsigned int hi = (unsigned int)f2bf(p2) | ((unsigned int)f2bf(p3) << 16);
      int colb = (kw + kt * 16 + gr * 4) * 2;
      uint2 pv; pv.x = lo; pv.y = hi;
      *reinterpret_cast<uint2*>(smem + px * 1024 + (colb ^ ((px & 7) << 4))) = pv;
    }
  }
  #pragma unroll
  for (int pt = 0; pt < 8; ++pt){
    s[pt] += __shfl_xor(s[pt], 16, 64);
    s[pt] += __shfl_xor(s[pt], 32, 64);
  }
  if (gr == 0){
    #pragma unroll
    for (int pt = 0; pt < 8; ++pt) wbuf[w * 128 + pt * 16 + li] = s[pt];
  }
  // hoist GEMM2 ks=0 codebook loads (overlap bar3 + rz)
  short8 bvc[2];
  #pragma unroll
  for (int nt = 0; nt < 2; ++nt)
    bvc[nt] = *reinterpret_cast<const short8*>(
        nmTf + ((size_t)(w*2 + nt)*16 + 0)*512 + loff);
  __syncthreads();                             // bar3: P + wbuf(sums) ready
  if (t < 128){
    float sum = 0.f;
    #pragma unroll
    for (int ww = 0; ww < 8; ++ww) sum += wbuf[ww * 128 + t];
    rz[t] = 1.0f / sum;
  }
  // GEMM2: out tile = P @ new_m  (bv prefetch depth 1; wave w owns c in [w*32,+32))
  f32x4 acc2[8][2];                            // [mt: 128 px][nt]
  #pragma unroll
  for (int mt = 0; mt < 8; ++mt)
    #pragma unroll
    for (int nt = 0; nt < 2; ++nt)
      acc2[mt][nt] = (f32x4){0.f,0.f,0.f,0.f};
  #pragma unroll
  for (int ks = 0; ks < 16; ++ks){
    short8 bvn[2];
    if (ks < 15){
      #pragma unroll
      for (int nt = 0; nt < 2; ++nt)
        bvn[nt] = *reinterpret_cast<const short8*>(
            nmTf + ((size_t)(w*2 + nt)*16 + (ks+1))*512 + loff);
    }
    #pragma unroll
    for (int mt = 0; mt < 8; ++mt){
      int row = mt * 16 + li;
      short8 af = *reinterpret_cast<const short8*>(
          smem + row * 1024 + ((ks * 64 + gr * 16) ^ ((row & 7) << 4)));
      #pragma unroll
      for (int nt = 0; nt < 2; ++nt)
        acc2[mt][nt] = __builtin_amdgcn_mfma_f32_16x16x32_bf16(af, bvc[nt], acc2[mt][nt], 0, 0, 0);
    }
    if (ks < 15){
      #pragma unroll
      for (int nt = 0; nt < 2; ++nt) bvc[nt] = bvn[nt];
    }
  }
  __syncthreads();                             // bar4: P dead, rz visible
  // ---- score2 via LDS transpose, two 64-px halves; 1KB-contiguous wave stores ----
  float* s2 = score2 + (size_t)px0 * Kk;
  #pragma unroll
  for (int h = 0; h < 2; ++h){
    #pragma unroll
    for (int kt = 0; kt < 4; ++kt)
      #pragma unroll
      for (int pt2 = 0; pt2 < 4; ++pt2){
        int pxl = pt2 * 16 + li;               // local px in half
        int kb = (kw + kt * 16 + gr * 4) * 4;  // byte offset of k within row
        *reinterpret_cast<f32x4*>(smem + pxl * 2048 + (kb ^ ((pxl & 7) << 4)))
            = acc[kt][h * 4 + pt2];
      }
    __syncthreads();                           // tile ready
    #pragma unroll
    for (int r = 0; r < 8; ++r){
      int pxl = w * 8 + r;
      int px = h * 64 + pxl;
      #pragma unroll
      for (int j = 0; j < 2; ++j){
        int o = j * 1024 + l * 16;
        f32x4 v = *reinterpret_cast<const f32x4*>(smem + pxl * 2048 + (o ^ ((pxl & 7) << 4)));
        *reinterpret_cast<f32x4*>(s2 + (size_t)px * Kk + (o >> 2)) = v;
      }
    }
    __syncthreads();                           // stores' LDS reads done before reuse
  }
  // ---- out via LDS transpose [256 c][512 B rows]; 512B-contiguous segments ----
  #pragma unroll
  for (int mt = 0; mt < 8; ++mt){
    int pb = mt * 16 + gr * 4;
    f32x4 rzv = *reinterpret_cast<const f32x4*>(&rz[pb]);
    #pragma unroll
    for (int nt = 0; nt < 2; ++nt){
      int c = w * 32 + nt * 16 + li;
      f32x4 v;
      v[0] = acc2[mt][nt][0] * rzv[0];
      v[1] = acc2[mt][nt][1] * rzv[1];
      v[2] = acc2[mt][nt][2] * rzv[2];
      v[3] = acc2[mt][nt][3] * rzv[3];
      *reinterpret_cast<f32x4*>(smem + c * 512 + ((pb * 4) ^ ((c & 7) << 4))) = v;
    }
  }
  __syncthreads();                             // out tile ready
  int b = px0 >> 12, hw0 = px0 & 4095;
  #pragma unroll
  for (int i = 0; i < 16; ++i){
    int c = w * 32 + i * 2 + (l >> 5);
    int o = (l & 31) * 16;
    f32x4 v = *reinterpret_cast<const f32x4*>(smem + c * 512 + (o ^ ((c & 7) << 4)));
    *reinterpret_cast<f32x4*>(out + ((size_t)b * Cc + c) * HW + hw0 + (o >> 2)) = v;
  }
}

extern "C" void kernel_launch(void* const* d_in, const int* in_sizes, int n_in,
                              void* d_out, int out_size, void* d_ws, size_t ws_size,
                              hipStream_t stream) {
  (void)in_sizes; (void)n_in; (void)out_size; (void)ws_size;
  const float* x = (const float*)d_in[0];   // (16,256,64,64)
  const float* m = (const float*)d_in[1];   // (512,256)
  float* out    = (float*)d_out;                       // 16777216 f32
  float* score2 = (float*)d_out + (size_t)Nn * Cc;     // 33554432 f32

  char* ws = (char*)d_ws;
  unsigned short* xr   = (unsigned short*)(ws);                 // 33554432 B raw bf16 x, px-major
  float*          rsb  = (float*)(ws + 33554432);               //   262144 B  1/||x||
  unsigned short* mnf  = (unsigned short*)(ws + 33816576);      //   262144 B fragment-major
  int*            ei   = (int*)(ws + 34078720);                 //   262144 B
  float*          es4  = (float*)(ws + 34340864);               //  2097152 B
  float*          ec4  = (float*)(ws + 36438016);               //     8192 B
  unsigned short* mn2f = (unsigned short*)(ws + 36446208);      //   262144 B fragment-major
  unsigned short* nmTf = (unsigned short*)(ws + 36708352);      //   262144 B fragment-major

  k_mnorm       <<<512,  64,  0, stream>>>(m, mnf);
  k_prep_score  <<<1024, 512, 0, stream>>>(x, mnf, rsb, xr, ei);
  k_segsum      <<<2048, 256, 0, stream>>>(ei, xr, es4, ec4);
  k_update      <<<512,  64,  0, stream>>>(es4, ec4, m, mn2f, nmTf);
  k_out         <<<512,  512, 0, stream>>>(xr, rsb, mn2f, nmTf, out, score2);
}